// Round 5
// baseline (271.792 us; speedup 1.0000x reference)
//
#include <hip/hip_runtime.h>
#include <hip/hip_bf16.h>

typedef __bf16 bf16_t;
typedef __bf16 bf16x8 __attribute__((ext_vector_type(8)));
typedef float  f32x4  __attribute__((ext_vector_type(4)));

#define DM    512
#define NQKV  1536
#define NTOK  65536

// Static device scratch
__device__ __align__(16) bf16_t g_wt [(size_t)NQKV * DM];   // W^T, bf16 [n][k]
__device__ __align__(16) bf16_t g_xb [(size_t)NTOK * DM];   // x, bf16
__device__ __align__(16) bf16_t g_qkv[(size_t)NTOK * NQKV]; // qkv, bf16 [tok][1536]

typedef const void __attribute__((address_space(1)))* gas_t;
typedef void       __attribute__((address_space(3)))* sas_t;
__device__ __forceinline__ void gl_lds16(const void* g, void* s) {
    __builtin_amdgcn_global_load_lds((gas_t)g, (sas_t)s, 16, 0, 0);
}
#define MEMFENCE asm volatile("" ::: "memory")
#define BARRIER  do { MEMFENCE; __builtin_amdgcn_s_barrier(); MEMFENCE; } while (0)

// ---------------------------------------------------------------------------
// Kernel 1: transpose + convert W_q|W_k|W_v (fp32 [k][n]) -> g_wt (bf16 [n][k])
// ---------------------------------------------------------------------------
__global__ void prep_w(const float* __restrict__ Wq,
                       const float* __restrict__ Wk,
                       const float* __restrict__ Wv) {
    __shared__ float tile[32][33];
    int b   = blockIdx.x;                 // 3*16*16 = 768
    int mat = b >> 8;
    int kt  = (b >> 4) & 15;
    int nt  = b & 15;
    const float* W = (mat == 0) ? Wq : ((mat == 1) ? Wk : Wv);
    int tx = threadIdx.x & 31, ty = threadIdx.x >> 5;
#pragma unroll
    for (int p = 0; p < 4; ++p) {
        int kk = p * 8 + ty;
        tile[kk][tx] = W[(kt * 32 + kk) * DM + nt * 32 + tx];
    }
    __syncthreads();
#pragma unroll
    for (int p = 0; p < 4; ++p) {
        int rn = p * 8 + ty;
        int N  = mat * 512 + nt * 32 + rn;
        g_wt[(size_t)N * DM + kt * 32 + tx] = (bf16_t)tile[tx][rn];
    }
}

// ---------------------------------------------------------------------------
// Kernel 2: x fp32 -> bf16
// ---------------------------------------------------------------------------
__global__ void cvt_x(const float* __restrict__ x) {
    size_t i = (size_t)blockIdx.x * blockDim.x + threadIdx.x;
    const size_t n8 = (size_t)NTOK * DM / 8;
    const size_t stride = (size_t)gridDim.x * blockDim.x;
    for (; i < n8; i += stride) {
        const float4* gp = (const float4*)(x + i * 8);
        float4 f0 = gp[0], f1 = gp[1];
        bf16x8 v;
        v[0] = (bf16_t)f0.x; v[1] = (bf16_t)f0.y;
        v[2] = (bf16_t)f0.z; v[3] = (bf16_t)f0.w;
        v[4] = (bf16_t)f1.x; v[5] = (bf16_t)f1.y;
        v[6] = (bf16_t)f1.z; v[7] = (bf16_t)f1.w;
        *(bf16x8*)(g_xb + i * 8) = v;
    }
}

// ---------------------------------------------------------------------------
// Kernel 3: qkv = xb @ wt^T  (M=65536, N=1536, K=512)
// 256x256 tile, BK=64, 8 waves, 2x64KB LDS dbuf.
// m201-style freed-region pipeline: tile T+2 streams into tile T's buffer as
// phases free its strips; vmcnt(7) counted waits (never 0 until the end).
// ---------------------------------------------------------------------------
__global__ __launch_bounds__(512, 2) void gemm_qkv() {
    extern __shared__ char sm[];          // 131072 B: buf[2] x (A 32K | B 32K)

    const int tid = threadIdx.x;
    const int l   = tid & 63, w = tid >> 6;      // lane, wave 0..7
    const int lr  = l & 15, kg = l >> 4;         // frag row, k-group
    const int wr  = w >> 2, wc = w & 3;          // 2x4 wave grid -> 128x64/wave

    int raw = blockIdx.x;                         // 1536 blocks
    int bid = (raw & 7) * 192 + (raw >> 3);       // XCD swizzle (1536%8==0)
    int mt  = bid / 6, nt = bid - mt * 6;         // nt fastest: A-panel L2 reuse
    const size_t m0 = (size_t)mt * 256;
    const int    n0 = nt * 256;

    // ---- staging helpers (rule #21: linear LDS dest, inverse-swizzled src) -
    const int lrow8 = l >> 3;                     // 0..7: row within 8-row chunk
    const int schk  = (l & 7) ^ lrow8;            // source chunk (pre-swizzled)

    // A issue j covers the strip-pair freed by phase j: rows 32j..+31, 128+32j..+31
    auto stageA = [&](int t, int j) {
        int base_row = 32 * j + (w & 3) * 8 + ((w >> 2) << 7);   // wave-uniform
        const bf16_t* s = g_xb + (m0 + base_row + lrow8) * DM + t * 64 + schk * 8;
        gl_lds16(s, sm + (t & 1) * 65536 + base_row * 128);
    };
    // B issue j: rows 64j..+63 (all of B freed after phase 0)
    auto stageB = [&](int t, int j) {
        int base_row = 64 * j + w * 8;
        const bf16_t* s = g_wt + (size_t)(n0 + base_row + lrow8) * DM + t * 64 + schk * 8;
        gl_lds16(s, sm + (t & 1) * 65536 + 32768 + base_row * 128);
    };

    // ---- ds_read offsets (swizzled: chunk ^= row&7; row&7 == lr&7) --------
    const int c0   = ((kg ^ (lr & 7)) * 16);
    const int aoff = (wr * 128 + lr) * 128 + c0;            // + mi*2048, ^64 ks=1
    const int boff = 32768 + (wc * 64 + lr) * 128 + c0;     // + ni*2048, ^64 ks=1

    f32x4 acc[8][4];
#pragma unroll
    for (int a = 0; a < 8; ++a)
#pragma unroll
        for (int b = 0; b < 4; ++b) acc[a][b] = (f32x4){0.f, 0.f, 0.f, 0.f};

    // ---- prologue: tile0 fully (8 issues), tile1 first 7 ------------------
    stageB(0, 0); stageB(0, 1); stageA(0, 0);
    stageB(0, 2); stageB(0, 3); stageA(0, 1);
    stageA(0, 2); stageA(0, 3);
    stageB(1, 0); stageB(1, 1); stageA(1, 0);
    stageB(1, 2); stageB(1, 3); stageA(1, 1);
    stageA(1, 2);
    asm volatile("s_waitcnt vmcnt(7)" ::: "memory");   // tile0's 8 retired
    BARRIER;

    for (int t = 0; t < 8; ++t) {
        const int base = (t & 1) * 65536;
        bf16x8 bfrag[4][2];
#pragma unroll
        for (int q = 0; q < 4; ++q) {
            // ---- ds-loads for this phase ------------------------------------
            if (q == 0) {
#pragma unroll
                for (int ni = 0; ni < 4; ++ni) {
                    int o = base + boff + ni * 2048;
                    bfrag[ni][0] = *(const bf16x8*)(sm + o);
                    bfrag[ni][1] = *(const bf16x8*)(sm + (o ^ 64));
                }
            }
            bf16x8 af[2][2];
#pragma unroll
            for (int mm = 0; mm < 2; ++mm) {
                int o = base + aoff + (q * 2 + mm) * 2048;
                af[mm][0] = *(const bf16x8*)(sm + o);
                af[mm][1] = *(const bf16x8*)(sm + (o ^ 64));
            }
            // ---- staging into freed regions ---------------------------------
            if (q == 0) { if (t + 1 < 8) stageA(t + 1, 3); }             // strip3 freed at (t-1).q3
            if (q == 1 && t + 2 < 8) { stageB(t + 2, 0); stageB(t + 2, 1); stageA(t + 2, 0); }
            if (q == 2 && t + 2 < 8) { stageB(t + 2, 2); stageB(t + 2, 3); stageA(t + 2, 1); }
            if (q == 3 && t + 2 < 8) { stageA(t + 2, 2); }

            BARRIER;                      // all phase-q reads retired chip-wide
            __builtin_amdgcn_s_setprio(1);
#pragma unroll
            for (int mm = 0; mm < 2; ++mm)
#pragma unroll
                for (int ni = 0; ni < 4; ++ni) {
                    acc[q*2+mm][ni] = __builtin_amdgcn_mfma_f32_16x16x32_bf16(
                        af[mm][0], bfrag[ni][0], acc[q*2+mm][ni], 0, 0, 0);
                    acc[q*2+mm][ni] = __builtin_amdgcn_mfma_f32_16x16x32_bf16(
                        af[mm][1], bfrag[ni][1], acc[q*2+mm][ni], 0, 0, 0);
                }
            __builtin_amdgcn_s_setprio(0);
            if (q == 3) {
                // counted wait for NEXT tile's staging (placed before the
                // barrier so per-wave vmcnt + barrier => cross-wave safe)
                if (t < 6)       asm volatile("s_waitcnt vmcnt(7)" ::: "memory");
                else if (t == 6) asm volatile("s_waitcnt vmcnt(0)" ::: "memory");
            }
            BARRIER;
        }
    }

    // ---- epilogue: two-pass LDS roundtrip, [128][264] bf16 (conflict-free) -
    bf16_t* cds = (bf16_t*)sm;
#pragma unroll
    for (int p = 0; p < 2; ++p) {
        if (wr == p) {
#pragma unroll
            for (int mi = 0; mi < 8; ++mi)
#pragma unroll
                for (int ni = 0; ni < 4; ++ni)
#pragma unroll
                    for (int i = 0; i < 4; ++i)
                        cds[(mi * 16 + kg * 4 + i) * 264 + wc * 64 + ni * 16 + lr] =
                            (bf16_t)acc[mi][ni][i];
        }
        BARRIER;
#pragma unroll
        for (int j = 0; j < 8; ++j) {
            int idx = j * 512 + tid;               // 0..4095
            int row = idx >> 5, ch = (idx & 31) * 8;
            *(bf16x8*)(g_qkv + (m0 + p * 128 + row) * NQKV + n0 + ch) =
                *(const bf16x8*)(cds + row * 264 + ch);
        }
        if (p == 0) BARRIER;
    }
}

// ---------------------------------------------------------------------------
// Kernel 4: per-token cross-head attention. 16 tokens/block, K/V staged in LDS.
// ---------------------------------------------------------------------------
__global__ __launch_bounds__(256) void attn_x(float* __restrict__ out) {
    __shared__ __align__(16) char sm[32768];   // [tok][k 512 | v 512] bf16
    const int tid = threadIdx.x, l = tid & 63, w = tid >> 6;
    const size_t tok0 = (size_t)blockIdx.x * 16;
    const char* src = (const char*)g_qkv + tok0 * 3072;

#pragma unroll
    for (int i = 0; i < 8; ++i) {
        int b = (w * 8 + i) << 10;
        gl_lds16(src + (b >> 11) * 3072 + 1024 + (b & 2047) + l * 16, sm + b);
    }

    const int tok = tid >> 4, tj = tid & 15, h = tj & 7, d0 = (tj >> 3) << 5;

    float qv[32];
    {
        const bf16_t* qp = g_qkv + (tok0 + tok) * NQKV + h * 64 + d0;
#pragma unroll
        for (int j = 0; j < 4; ++j) {
            bf16x8 q8 = *(const bf16x8*)(qp + 8 * j);
#pragma unroll
            for (int e = 0; e < 8; ++e) qv[8 * j + e] = (float)q8[e];
        }
    }
    __syncthreads();

    const bf16_t* base = (const bf16_t*)sm + tok * 1024;
    float s[8];
#pragma unroll
    for (int t = 0; t < 8; ++t) {
        const bf16_t* kp = base + t * 64 + d0;
        float a = 0.f;
#pragma unroll
        for (int j = 0; j < 4; ++j) {
            bf16x8 k8 = *(const bf16x8*)(kp + 8 * j);
#pragma unroll
            for (int e = 0; e < 8; ++e) a += qv[8 * j + e] * (float)k8[e];
        }
        s[t] = a;
    }
#pragma unroll
    for (int t = 0; t < 8; ++t) s[t] += __shfl_xor(s[t], 8, 64);

    float m = s[0];
#pragma unroll
    for (int t = 1; t < 8; ++t) m = fmaxf(m, s[t]);
    float p[8], psum = 0.f;
#pragma unroll
    for (int t = 0; t < 8; ++t) {
        p[t] = exp2f((s[t] - m) * 1.44269504088896f);
        psum += p[t];
    }
    float inv = 1.0f / psum;

    float o[32];
#pragma unroll
    for (int e = 0; e < 32; ++e) o[e] = 0.f;
#pragma unroll
    for (int t = 0; t < 8; ++t) {
        float pt = p[t] * inv;
        const bf16_t* vp = base + 512 + t * 64 + d0;
#pragma unroll
        for (int j = 0; j < 4; ++j) {
            bf16x8 v8 = *(const bf16x8*)(vp + 8 * j);
#pragma unroll
            for (int e = 0; e < 8; ++e) o[8 * j + e] += pt * (float)v8[e];
        }
    }

    float* op = out + (tok0 + tok) * DM + h * 64 + d0;
#pragma unroll
    for (int j = 0; j < 8; ++j) {
        float4 o4 = {o[4 * j], o[4 * j + 1], o[4 * j + 2], o[4 * j + 3]};
        *(float4*)(op + 4 * j) = o4;
    }
}

// ---------------------------------------------------------------------------
extern "C" void kernel_launch(void* const* d_in, const int* in_sizes, int n_in,
                              void* d_out, int out_size, void* d_ws, size_t ws_size,
                              hipStream_t stream) {
    const float* x  = (const float*)d_in[0];
    const float* Wq = (const float*)d_in[1];
    const float* Wk = (const float*)d_in[2];
    const float* Wv = (const float*)d_in[3];
    float* out = (float*)d_out;

    prep_w<<<768, 256, 0, stream>>>(Wq, Wk, Wv);
    cvt_x<<<2048, 256, 0, stream>>>(x);
    gemm_qkv<<<1536, 512, 131072, stream>>>();   // 256 m-tiles x 6 n-tiles
    attn_x<<<4096, 256, 0, stream>>>(out);       // 16 tokens per block
}

// Round 6
// 202.804 us; speedup vs baseline: 1.3402x; 1.3402x over previous
//
#include <hip/hip_runtime.h>
#include <hip/hip_bf16.h>

typedef __bf16 bf16_t;
typedef __bf16 bf16x8 __attribute__((ext_vector_type(8)));
typedef float  f32x4  __attribute__((ext_vector_type(4)));

#define DM    512
#define NQKV  1536
#define NTOK  65536
#define TM    32          // tokens per block
#define QSTR  1544        // qkv LDS row stride (elems): 1536 + 8 pad (3088 B)

// Fragment-major repacked weights ("flatmm shuffle"): for wave w (0..7),
// K-step s (0..15), ni (0..11), lane l (0..63), elem e (0..7):
//   g_wt2[(((w*16+s)*12+ni)*64 + l)*8 + e] = W^T[n][k]
//   with n = w*192+ni*16+(l&15), k = s*32+(l>>4)*8+e.
// A wave's per-step B load is then 12 x lane-contiguous 1KB dwordx4 streams.
__device__ __align__(16) bf16_t g_wt2[(size_t)NQKV * DM];

#define MEMFENCE asm volatile("" ::: "memory")

// ---------------------------------------------------------------------------
// Kernel 1: scatter W_q|W_k|W_v (fp32 [k][n]) -> g_wt2 fragment-major bf16
// ---------------------------------------------------------------------------
__global__ void prep_w2(const float* __restrict__ Wq,
                        const float* __restrict__ Wk,
                        const float* __restrict__ Wv) {
    int flat = blockIdx.x * 256 + threadIdx.x;   // 0..98303 (one bf16x8 each)
    int l  = flat & 63;
    int kg = l >> 4, lr = l & 15;
    int t2 = flat >> 6;
    int ni = t2 % 12;
    int t3 = t2 / 12;
    int s  = t3 & 15, w = t3 >> 4;
    int n  = w * 192 + ni * 16 + lr;             // 0..1535
    int k0 = s * 32 + kg * 8;
    int mat = n >> 9, nn = n & 511;
    const float* W = (mat == 0) ? Wq : ((mat == 1) ? Wk : Wv);
    bf16x8 v;
#pragma unroll
    for (int e = 0; e < 8; ++e) v[e] = (bf16_t)W[(k0 + e) * DM + nn];
    *(bf16x8*)(g_wt2 + (size_t)flat * 8) = v;
}

// ---------------------------------------------------------------------------
// Kernel 2: fused QKV projection + cross-head attention, flatmm-style.
// 32 tokens/block, 8 waves. A (x tile) in LDS; B streamed global->reg->MFMA
// (2-deep register dbuf, barrier-free K-loop); qkv stays in LDS; attention
// reuses the R3-validated math; out written directly.
// ---------------------------------------------------------------------------
__global__ __launch_bounds__(512, 1) void fused_mha(
    const float* __restrict__ x, float* __restrict__ out) {
    extern __shared__ char sm[];        // qkv [32][QSTR] bf16 = 98816 B
    // A tile [32][512] bf16 chunk-swizzled aliases sm[0..32768) (dead after K-loop)

    const int tid = threadIdx.x;
    const int l   = tid & 63, w = tid >> 6;
    const int lr  = l & 15,  kg = l >> 4;
    const size_t tok0 = (size_t)blockIdx.x * TM;

    // ---- stage x tile: fp32 global -> bf16 LDS, 16B-chunk XOR swizzle ------
    {
        const int r = tid >> 4, tj = tid & 15, r7 = r & 7;
        const float* xp = x + (tok0 + r) * DM;
#pragma unroll
        for (int j = 0; j < 4; ++j) {
            int c = tj + j * 16;                  // chunk 0..63 (8 bf16 each)
            float4 f0 = *(const float4*)(xp + c * 8);
            float4 f1 = *(const float4*)(xp + c * 8 + 4);
            bf16x8 v;
            v[0] = (bf16_t)f0.x; v[1] = (bf16_t)f0.y;
            v[2] = (bf16_t)f0.z; v[3] = (bf16_t)f0.w;
            v[4] = (bf16_t)f1.x; v[5] = (bf16_t)f1.y;
            v[6] = (bf16_t)f1.z; v[7] = (bf16_t)f1.w;
            *(bf16x8*)(sm + r * 1024 + ((c ^ r7) << 4)) = v;
        }
    }

    // ---- B prefetch: steps 0,1 into register double-buffer ----------------
    const bf16_t* gw = g_wt2 + ((size_t)w * 16 * 12 * 64 + l) * 8;
    bf16x8 bufA[12], bufB[12];
#pragma unroll
    for (int ni = 0; ni < 12; ++ni)
        bufA[ni] = *(const bf16x8*)(gw + ni * 512);
#pragma unroll
    for (int ni = 0; ni < 12; ++ni)
        bufB[ni] = *(const bf16x8*)(gw + 6144 + ni * 512);

    // my ds_writes done (B reg-loads may stay outstanding across the barrier)
    asm volatile("s_waitcnt lgkmcnt(0)" ::: "memory");
    __builtin_amdgcn_s_barrier();
    MEMFENCE;

    // ---- barrier-free K-loop: 16 steps, 24 MFMA/step, B 2-deep prefetch ---
    f32x4 acc[2][12];
#pragma unroll
    for (int a = 0; a < 2; ++a)
#pragma unroll
        for (int b = 0; b < 12; ++b) acc[a][b] = (f32x4){0.f, 0.f, 0.f, 0.f};

    const int sx = (lr & 7) << 4;               // A-read swizzle term

#define AREAD(dst, s_) do {                                                   \
        dst[0] = *(const bf16x8*)(sm + lr * 1024 +                            \
                                  (((s_) * 64 + kg * 16) ^ sx));              \
        dst[1] = *(const bf16x8*)(sm + 16384 + lr * 1024 +                    \
                                  (((s_) * 64 + kg * 16) ^ sx));              \
    } while (0)

#define MFMA_STEP(AF, BUF)                                                    \
    _Pragma("unroll")                                                         \
    for (int mi = 0; mi < 2; ++mi)                                            \
    _Pragma("unroll")                                                         \
    for (int ni = 0; ni < 12; ++ni)                                           \
        acc[mi][ni] = __builtin_amdgcn_mfma_f32_16x16x32_bf16(                \
            AF[mi], BUF[ni], acc[mi][ni], 0, 0, 0);

#pragma unroll
    for (int sp = 0; sp < 8; ++sp) {
        const int s0 = sp * 2, s1 = s0 + 1;
        bf16x8 af0[2], af1[2];
        AREAD(af0, s0);
        AREAD(af1, s1);                           // issued early: covered by MFMA(af0)
        MFMA_STEP(af0, bufA);
        if (sp < 7) {                             // refill bufA <- step s0+2
#pragma unroll
            for (int ni = 0; ni < 12; ++ni)
                bufA[ni] = *(const bf16x8*)(gw + (s0 + 2) * 6144 + ni * 512);
        }
        MFMA_STEP(af1, bufB);
        if (sp < 7) {                             // refill bufB <- step s1+2
#pragma unroll
            for (int ni = 0; ni < 12; ++ni)
                bufB[ni] = *(const bf16x8*)(gw + (s1 + 2) * 6144 + ni * 512);
        }
    }
#undef AREAD
#undef MFMA_STEP

    // ---- A region dead; all waves synced before qkv overwrites it ---------
    MEMFENCE;
    __builtin_amdgcn_s_barrier();
    MEMFENCE;

    // ---- epilogue: acc -> qkv LDS [32][QSTR] (row = token, col = n) --------
    bf16_t* qkv = (bf16_t*)sm;
#pragma unroll
    for (int mi = 0; mi < 2; ++mi)
#pragma unroll
        for (int ni = 0; ni < 12; ++ni) {
            int col = w * 192 + ni * 16 + lr;
#pragma unroll
            for (int i = 0; i < 4; ++i) {
                int token = mi * 16 + kg * 4 + i;
                qkv[token * QSTR + col] = (bf16_t)acc[mi][ni][i];
            }
        }
    asm volatile("s_waitcnt lgkmcnt(0)" ::: "memory");
    __builtin_amdgcn_s_barrier();
    MEMFENCE;

    // ---- attention: 16 threads per token (R3-validated math) ---------------
    const int tok = tid >> 4, tj = tid & 15, h = tj & 7, d0 = (tj >> 3) << 5;
    const bf16_t* base = qkv + tok * QSTR;

    float qv[32];
    {
        const bf16_t* qp = base + h * 64 + d0;
#pragma unroll
        for (int j = 0; j < 4; ++j) {
            bf16x8 q8 = *(const bf16x8*)(qp + 8 * j);
#pragma unroll
            for (int e = 0; e < 8; ++e) qv[8 * j + e] = (float)q8[e];
        }
    }

    float s[8];
#pragma unroll
    for (int t = 0; t < 8; ++t) {
        const bf16_t* kp = base + 512 + t * 64 + d0;
        float a = 0.f;
#pragma unroll
        for (int j = 0; j < 4; ++j) {
            bf16x8 k8 = *(const bf16x8*)(kp + 8 * j);
#pragma unroll
            for (int e = 0; e < 8; ++e) a += qv[8 * j + e] * (float)k8[e];
        }
        s[t] = a;
    }
#pragma unroll
    for (int t = 0; t < 8; ++t) s[t] += __shfl_xor(s[t], 8, 64);  // d-half combine

    float m = s[0];
#pragma unroll
    for (int t = 1; t < 8; ++t) m = fmaxf(m, s[t]);
    float p[8], psum = 0.f;
#pragma unroll
    for (int t = 0; t < 8; ++t) {
        p[t] = exp2f((s[t] - m) * 1.44269504088896f);
        psum += p[t];
    }
    float inv = 1.0f / psum;

    float o[32];
#pragma unroll
    for (int e = 0; e < 32; ++e) o[e] = 0.f;
#pragma unroll
    for (int t = 0; t < 8; ++t) {
        float pt = p[t] * inv;
        const bf16_t* vp = base + 1024 + t * 64 + d0;
#pragma unroll
        for (int j = 0; j < 4; ++j) {
            bf16x8 v8 = *(const bf16x8*)(vp + 8 * j);
#pragma unroll
            for (int e = 0; e < 8; ++e) o[8 * j + e] += pt * (float)v8[e];
        }
    }

    float* op = out + (tok0 + tok) * DM + h * 64 + d0;
#pragma unroll
    for (int j = 0; j < 8; ++j) {
        float4 o4 = {o[4 * j], o[4 * j + 1], o[4 * j + 2], o[4 * j + 3]};
        *(float4*)(op + 4 * j) = o4;
    }
}

// ---------------------------------------------------------------------------
extern "C" void kernel_launch(void* const* d_in, const int* in_sizes, int n_in,
                              void* d_out, int out_size, void* d_ws, size_t ws_size,
                              hipStream_t stream) {
    (void)d_ws; (void)ws_size; (void)n_in; (void)out_size;
    const float* x  = (const float*)d_in[0];
    const float* Wq = (const float*)d_in[1];
    const float* Wk = (const float*)d_in[2];
    const float* Wv = (const float*)d_in[3];
    float* out = (float*)d_out;

    int ntok = in_sizes[0] / DM;                  // 65536
    prep_w2<<<384, 256, 0, stream>>>(Wq, Wk, Wv);
    size_t lds = (size_t)TM * QSTR * sizeof(bf16_t);   // 98816 B
    fused_mha<<<ntok / TM, 512, lds, stream>>>(x, out);
}